// Round 5
// baseline (775.287 us; speedup 1.0000x reference)
//
#include <hip/hip_runtime.h>
#include <hip/hip_bf16.h>
#include <math.h>

#define S_LEN  2048
#define DMODEL 2560
#define NHEADS 32
#define NKV    8
#define HD     128
#define QKDIM  (NHEADS * HD)   // 4096
#define KVDIM  (NKV * HD)      // 1024
#define KVCAT  (2 * KVDIM)     // 2048 (K and V concatenated per row)

typedef __bf16 bf16x8 __attribute__((ext_vector_type(8)));
typedef float  f32x4  __attribute__((ext_vector_type(4)));
typedef unsigned short u16;

#define AS1 __attribute__((address_space(1)))
#define AS3 __attribute__((address_space(3)))

__device__ __forceinline__ void load16_to_lds(const void* g, void* l) {
    __builtin_amdgcn_global_load_lds((const AS1 void*)g, (AS3 void*)l, 16, 0, 0);
}

__device__ __forceinline__ u16 f2bf(float f) {
    unsigned u = __builtin_bit_cast(unsigned, f);
    return (u16)((u + 0x7fff + ((u >> 16) & 1)) >> 16);   // RTNE
}

// ---------------------------------------------------------------------------
// fp32 -> bf16 convert, 4 elements/thread, grid-stride. n4 = n/4.
// ---------------------------------------------------------------------------
__global__ __launch_bounds__(256) void f32_to_bf16_k(const float* __restrict__ in,
                                                     u16* __restrict__ out, int n4) {
    int i = blockIdx.x * 256 + threadIdx.x;
    const int stride = gridDim.x * 256;
    for (; i < n4; i += stride) {
        float4 v = ((const float4*)in)[i];
        ushort4 r;
        r.x = f2bf(v.x); r.y = f2bf(v.y); r.z = f2bf(v.z); r.w = f2bf(v.w);
        ((ushort4*)out)[i] = r;
    }
}

// ---------------------------------------------------------------------------
// RoPE table: ct/st[s][i] fp32, computed in double (131K threads, trivial).
// ---------------------------------------------------------------------------
__global__ __launch_bounds__(64) void rope_table(float* __restrict__ ct,
                                                 float* __restrict__ st) {
    const int s = blockIdx.x;
    const int i = threadIdx.x;           // 0..63
    const double invf = pow(5.0e6, -(double)i / 64.0);
    const double ang  = (double)s * invf;
    ct[s * 64 + i] = (float)cos(ang);
    st[s * 64 + i] = (float)sin(ang);
}

// ---------------------------------------------------------------------------
// bf16 MFMA NT GEMM, BK=64 (halved barrier count vs the BK=32 m97 pattern;
// LDS 32 KB total so no occupancy cliff, unlike BK=128's 64 KB).
// LDS layout: [mtile(8)][khalf(2)][lane(64)][8] fragment-chunk order.
// M%128==0, N%128==0, K%64==0 for all calls.
// ---------------------------------------------------------------------------
__global__ __launch_bounds__(256) void gemm_bf16_nt(const __bf16* __restrict__ A,
                                                    const __bf16* __restrict__ B,
                                                    float* __restrict__ C,
                                                    int M, int N, int K) {
    __shared__ __align__(16) __bf16 Als[128 * 64];   // 16 KB
    __shared__ __align__(16) __bf16 Bls[128 * 64];   // 16 KB
    const int tid  = threadIdx.x;
    const int lane = tid & 63;
    const int wave = tid >> 6;
    const int wm   = wave >> 1, wn = wave & 1;
    const int m0   = blockIdx.y * 128;
    const int n0   = blockIdx.x * 128;
    const int frow = lane & 15;
    const int fkq  = lane >> 4;

    f32x4 acc[4][4];
#pragma unroll
    for (int t = 0; t < 4; ++t)
#pragma unroll
        for (int u = 0; u < 4; ++u)
            acc[t][u] = (f32x4){0.f, 0.f, 0.f, 0.f};

    for (int k0 = 0; k0 < K; k0 += 64) {
        __syncthreads();
#pragma unroll
        for (int i = 0; i < 2; ++i) {
            const int mt  = i * 4 + wave;
            const int row = mt * 16 + frow;
#pragma unroll
            for (int kh = 0; kh < 2; ++kh) {
                const int col = k0 + kh * 32 + fkq * 8;
                load16_to_lds(A + (size_t)(m0 + row) * K + col,
                              &Als[(size_t)((mt * 2 + kh) * 64) * 8]);
                load16_to_lds(B + (size_t)(n0 + row) * K + col,
                              &Bls[(size_t)((mt * 2 + kh) * 64) * 8]);
            }
        }
        __syncthreads();

#pragma unroll
        for (int kh = 0; kh < 2; ++kh) {
            bf16x8 af[4], bfr[4];
#pragma unroll
            for (int t = 0; t < 4; ++t)
                af[t]  = *(const bf16x8*)&Als[(((wm * 4 + t) * 2 + kh) * 64 + lane) * 8];
#pragma unroll
            for (int u = 0; u < 4; ++u)
                bfr[u] = *(const bf16x8*)&Bls[(((wn * 4 + u) * 2 + kh) * 64 + lane) * 8];
#pragma unroll
            for (int t = 0; t < 4; ++t)
#pragma unroll
                for (int u = 0; u < 4; ++u)
                    acc[t][u] = __builtin_amdgcn_mfma_f32_16x16x32_bf16(
                                    af[t], bfr[u], acc[t][u], 0, 0, 0);
        }
    }

    const int crow = (lane >> 4) * 4;
    const int ccol = lane & 15;
#pragma unroll
    for (int t = 0; t < 4; ++t) {
        const int gr = m0 + (wm * 4 + t) * 16 + crow;
#pragma unroll
        for (int u = 0; u < 4; ++u) {
            const int gc = n0 + (wn * 4 + u) * 16 + ccol;
#pragma unroll
            for (int r = 0; r < 4; ++r)
                C[(size_t)(gr + r) * N + gc] = acc[t][u][r];
        }
    }
}

// ---------------------------------------------------------------------------
// Fused QKV GEMM, BK=64.  grid (48,16): n-tiles [0,32) -> Wq/Cq[2048][4096];
// [32,48) -> (Wk||Wv)/Ckv[2048][2048].  K = DMODEL = 2560 -> 40 iters.
// ---------------------------------------------------------------------------
__global__ __launch_bounds__(256) void gemm_qkv(const __bf16* __restrict__ A,
                                                const __bf16* __restrict__ Bq,
                                                const __bf16* __restrict__ Bkv,
                                                float* __restrict__ Cq,
                                                float* __restrict__ Ckv) {
    __shared__ __align__(16) __bf16 Als[128 * 64];
    __shared__ __align__(16) __bf16 Bls[128 * 64];
    const int K = DMODEL;
    const int n0g = blockIdx.x * 128;
    const __bf16* B;
    float* C;
    int ldc, n0;
    if (n0g < QKDIM) { B = Bq;  C = Cq;  ldc = QKDIM; n0 = n0g; }
    else             { B = Bkv; C = Ckv; ldc = KVCAT; n0 = n0g - QKDIM; }

    const int tid  = threadIdx.x;
    const int lane = tid & 63;
    const int wave = tid >> 6;
    const int wm   = wave >> 1, wn = wave & 1;
    const int m0   = blockIdx.y * 128;
    const int frow = lane & 15;
    const int fkq  = lane >> 4;

    f32x4 acc[4][4];
#pragma unroll
    for (int t = 0; t < 4; ++t)
#pragma unroll
        for (int u = 0; u < 4; ++u)
            acc[t][u] = (f32x4){0.f, 0.f, 0.f, 0.f};

    for (int k0 = 0; k0 < K; k0 += 64) {
        __syncthreads();
#pragma unroll
        for (int i = 0; i < 2; ++i) {
            const int mt  = i * 4 + wave;
            const int row = mt * 16 + frow;
#pragma unroll
            for (int kh = 0; kh < 2; ++kh) {
                const int col = k0 + kh * 32 + fkq * 8;
                load16_to_lds(A + (size_t)(m0 + row) * K + col,
                              &Als[(size_t)((mt * 2 + kh) * 64) * 8]);
                load16_to_lds(B + (size_t)(n0 + row) * K + col,
                              &Bls[(size_t)((mt * 2 + kh) * 64) * 8]);
            }
        }
        __syncthreads();

#pragma unroll
        for (int kh = 0; kh < 2; ++kh) {
            bf16x8 af[4], bfr[4];
#pragma unroll
            for (int t = 0; t < 4; ++t)
                af[t]  = *(const bf16x8*)&Als[(((wm * 4 + t) * 2 + kh) * 64 + lane) * 8];
#pragma unroll
            for (int u = 0; u < 4; ++u)
                bfr[u] = *(const bf16x8*)&Bls[(((wn * 4 + u) * 2 + kh) * 64 + lane) * 8];
#pragma unroll
            for (int t = 0; t < 4; ++t)
#pragma unroll
                for (int u = 0; u < 4; ++u)
                    acc[t][u] = __builtin_amdgcn_mfma_f32_16x16x32_bf16(
                                    af[t], bfr[u], acc[t][u], 0, 0, 0);
        }
    }

    const int crow = (lane >> 4) * 4;
    const int ccol = lane & 15;
#pragma unroll
    for (int t = 0; t < 4; ++t) {
        const int gr = m0 + (wm * 4 + t) * 16 + crow;
#pragma unroll
        for (int u = 0; u < 4; ++u) {
            const int gc = n0 + (wn * 4 + u) * 16 + ccol;
#pragma unroll
            for (int r = 0; r < 4; ++r)
                C[(size_t)(gr + r) * ldc + gc] = acc[t][u][r];
        }
    }
}

// ---------------------------------------------------------------------------
// Per-(s, head) RMSNorm + RoPE, table-driven.
// ---------------------------------------------------------------------------
__global__ __launch_bounds__(128) void norm_rope(const float* __restrict__ qg,
                                                 const float* __restrict__ kv,
                                                 const float* __restrict__ ct,
                                                 const float* __restrict__ st,
                                                 const float* __restrict__ qw,
                                                 const float* __restrict__ kw,
                                                 u16* __restrict__ qrb,
                                                 float* __restrict__ kc,
                                                 u16* __restrict__ kcb,
                                                 float* __restrict__ vc) {
    const int slot = blockIdx.x;   // 0..39
    const int s    = blockIdx.y;   // 0..2047
    const int d    = threadIdx.x;  // 0..127

    float x;
    const float* w;
    if (slot < NHEADS) {
        x = qg[(size_t)s * QKDIM + slot * HD + d];
        w = qw;
    } else {
        const int g = slot - NHEADS;
        x = kv[(size_t)s * KVCAT + g * HD + d];
        w = kw;
        vc[((size_t)g * S_LEN + s) * HD + d] =
            kv[(size_t)s * KVCAT + KVDIM + g * HD + d];
    }

    float ssum = x * x;
#pragma unroll
    for (int off = 1; off < 64; off <<= 1) ssum += __shfl_xor(ssum, off);
    __shared__ float red[2];
    __shared__ float ynorm[128];
    if ((d & 63) == 0) red[d >> 6] = ssum;
    __syncthreads();
    const float mean = (red[0] + red[1]) * (1.0f / 128.0f);
    const float y = x * rsqrtf(mean + 1e-6f) * w[d];
    ynorm[d] = y;
    __syncthreads();
    const float partner = ynorm[d ^ 64];

    const int i = d & 63;
    const float cs = ct[s * 64 + i];
    const float sn = st[s * 64 + i];
    const float outv = (d < 64) ? (y * cs - partner * sn)
                                : (y * cs + partner * sn);

    if (slot < NHEADS) {
        qrb[((size_t)slot * S_LEN + s) * HD + d] = f2bf(outv * 0.12751743f);
    } else {
        const int g = slot - NHEADS;
        kc [((size_t)g * S_LEN + s) * HD + d] = outv;
        kcb[((size_t)g * S_LEN + s) * HD + d] = f2bf(outv);
    }
}

// ---------------------------------------------------------------------------
// V transpose: kv fp32 [s][1024 + g*128+d]  ->  vtb bf16 [g][d][s]
// ---------------------------------------------------------------------------
__global__ __launch_bounds__(256) void v_transpose(const float* __restrict__ kv,
                                                   u16* __restrict__ vtb) {
    __shared__ float Ts[64][65];
    const int g  = blockIdx.x;
    const int s0 = blockIdx.y * 64;
    const int d0 = blockIdx.z * 64;
    const int tid = threadIdx.x;

    for (int e = tid; e < 64 * 16; e += 256) {
        const int r = e >> 4, c = (e & 15) << 2;
        float4 v = *(const float4*)(kv + (size_t)(s0 + r) * KVCAT + KVDIM
                                       + g * HD + d0 + c);
        Ts[r][c] = v.x; Ts[r][c+1] = v.y; Ts[r][c+2] = v.z; Ts[r][c+3] = v.w;
    }
    __syncthreads();
    for (int e = tid; e < 64 * 16; e += 256) {
        const int d = e >> 4, c = (e & 15) << 2;
        ushort4 o;
        o.x = f2bf(Ts[c+0][d]); o.y = f2bf(Ts[c+1][d]);
        o.z = f2bf(Ts[c+2][d]); o.w = f2bf(Ts[c+3][d]);
        *(ushort4*)(vtb + ((size_t)g * HD + d0 + d) * S_LEN + s0 + c) = o;
    }
}

// ---------------------------------------------------------------------------
// MFMA flash attention v3: 128-query tile per block (K/V staging bytes per
// Q-row halved vs v2).  Wave w owns mtiles {2w, 2w+1} (rows w*32..w*32+31).
// Q staged once into the 32KB QKV buffer, hoisted to regs, buffer reused for
// K (groups 0-15) + V^T (groups 16-31) each K-tile.  Fully-masked mtiles
// skip compute wave-uniformly (state unchanged == alpha=1, psum=0).
// LDS = 32 (QKV) + 16 (P) = 48 KB.
// ---------------------------------------------------------------------------
__global__ __launch_bounds__(256, 3) void attn_mfma(const __bf16* __restrict__ Qb,
                                                    const __bf16* __restrict__ Kb,
                                                    const __bf16* __restrict__ Vt,
                                                    u16* __restrict__ Ob) {
    __shared__ __align__(16) __bf16 QKV[32 * 64 * 8];   // 32 KB
    __shared__ __align__(16) __bf16 Pls[16 * 64 * 8];   // 16 KB

    const int h    = blockIdx.y;
    const int g    = h >> 2;
    const int q0   = blockIdx.x * 128;
    const int tid  = threadIdx.x;
    const int lane = tid & 63;
    const int wave = tid >> 6;
    const int fr   = lane & 15;
    const int fq   = lane >> 4;

    // stage Q (mt 0..7 x ks 0..3 = 32 groups), hoist wave's 2 mtiles to regs
#pragma unroll
    for (int i = 0; i < 2; ++i) {
        const int mt = wave * 2 + i;
        const __bf16* Qg = Qb + ((size_t)h * S_LEN + q0 + mt * 16 + fr) * HD;
#pragma unroll
        for (int ks = 0; ks < 4; ++ks)
            load16_to_lds(Qg + ks * 32 + fq * 8, &QKV[(size_t)((mt * 4 + ks) * 64) * 8]);
    }
    __syncthreads();
    bf16x8 aq[2][4];
#pragma unroll
    for (int i = 0; i < 2; ++i)
#pragma unroll
        for (int ks = 0; ks < 4; ++ks)
            aq[i][ks] = *(const bf16x8*)&QKV[(((wave * 2 + i) * 4 + ks) * 64 + lane) * 8];

    float m_i[2][4], l_i[2][4];
    f32x4 o_acc[2][8];
#pragma unroll
    for (int i = 0; i < 2; ++i) {
#pragma unroll
        for (int r = 0; r < 4; ++r) { m_i[i][r] = -INFINITY; l_i[i][r] = 0.0f; }
#pragma unroll
        for (int dt = 0; dt < 8; ++dt) o_acc[i][dt] = (f32x4){0.f, 0.f, 0.f, 0.f};
    }

    const int kt_max = blockIdx.x * 2 + 1;
    for (int kt = 0; kt <= kt_max; ++kt) {
        __syncthreads();   // prev iter's LDS reads (and Q hoist) done
        // stage K tile: wave w -> ntile w, groups 0-15
        {
            const __bf16* Kg = Kb + ((size_t)g * S_LEN + kt * 64 + wave * 16 + fr) * HD;
#pragma unroll
            for (int ks = 0; ks < 4; ++ks)
                load16_to_lds(Kg + ks * 32 + fq * 8, &QKV[(size_t)((wave * 4 + ks) * 64) * 8]);
        }
        // stage V^T tile: wave w -> dtiles {2w, 2w+1}, groups 16-31
#pragma unroll
        for (int i = 0; i < 2; ++i) {
            const int dt = wave * 2 + i;
            const __bf16* Vg = Vt + ((size_t)g * HD + dt * 16 + fr) * S_LEN + kt * 64;
#pragma unroll
            for (int ks = 0; ks < 2; ++ks)
                load16_to_lds(Vg + ks * 32 + fq * 8,
                              &QKV[(size_t)((16 + dt * 2 + ks) * 64) * 8]);
        }
        __syncthreads();   // staging complete

        // ---- per-mtile: QK^T, softmax, P write ----
#pragma unroll
        for (int i = 0; i < 2; ++i) {
            const int mt = wave * 2 + i;
            if (kt * 64 > q0 + mt * 16 + 15) continue;   // fully masked: skip

            f32x4 s_acc[4];
#pragma unroll
            for (int u = 0; u < 4; ++u) s_acc[u] = (f32x4){0.f, 0.f, 0.f, 0.f};
#pragma unroll
            for (int u = 0; u < 4; ++u)
#pragma unroll
                for (int ks = 0; ks < 4; ++ks)
                    s_acc[u] = __builtin_amdgcn_mfma_f32_16x16x32_bf16(
                                   aq[i][ks],
                                   *(const bf16x8*)&QKV[((u * 4 + ks) * 64 + lane) * 8],
                                   s_acc[u], 0, 0, 0);

            // causal mask only where the tile straddles the diagonal
            if (kt * 64 + 63 > q0 + mt * 16) {
#pragma unroll
                for (int u = 0; u < 4; ++u)
#pragma unroll
                    for (int r = 0; r < 4; ++r)
                        if (kt * 64 + u * 16 + fr > q0 + mt * 16 + fq * 4 + r)
                            s_acc[u][r] = -INFINITY;
            }

#pragma unroll
            for (int r = 0; r < 4; ++r) {
                float mx = fmaxf(fmaxf(s_acc[0][r], s_acc[1][r]),
                                 fmaxf(s_acc[2][r], s_acc[3][r]));
#pragma unroll
                for (int off = 1; off < 16; off <<= 1)
                    mx = fmaxf(mx, __shfl_xor(mx, off));
                const float m_new = fmaxf(m_i[i][r], mx);
                const float alpha = exp2f(m_i[i][r] - m_new);
                m_i[i][r] = m_new;

                float p[4], psum = 0.0f;
#pragma unroll
                for (int u = 0; u < 4; ++u) {
                    p[u] = exp2f(s_acc[u][r] - m_new);
                    psum += p[u];
                }
#pragma unroll
                for (int off = 1; off < 16; off <<= 1)
                    psum += __shfl_xor(psum, off);
                l_i[i][r] = l_i[i][r] * alpha + psum;

#pragma unroll
                for (int dt = 0; dt < 8; ++dt) o_acc[i][dt][r] *= alpha;

#pragma unroll
                for (int u = 0; u < 4; ++u) {
                    const int k = u * 16 + fr;
                    const int m = fq * 4 + r;
                    const int idx = ((mt * 2 + (k >> 5)) * 64
                                     + ((k >> 3) & 3) * 16 + m) * 8 + (k & 7);
                    ((u16*)Pls)[idx] = f2bf(p[u]);
                }
            }
        }

        // ---- PV (same-wave LDS write->read ordered; skip mirrors above) ----
#pragma unroll
        for (int i = 0; i < 2; ++i) {
            const int mt = wave * 2 + i;
            if (kt * 64 > q0 + mt * 16 + 15) continue;
            bf16x8 ap[2];
#pragma unroll
            for (int ks = 0; ks < 2; ++ks)
                ap[ks] = *(const bf16x8*)&Pls[((mt * 2 + ks) * 64 + lane) * 8];
#pragma unroll
            for (int dt = 0; dt < 8; ++dt)
#pragma unroll
                for (int ks = 0; ks < 2; ++ks)
                    o_acc[i][dt] = __builtin_amdgcn_mfma_f32_16x16x32_bf16(
                                       ap[ks],
                                       *(const bf16x8*)&QKV[((16 + dt * 2 + ks) * 64 + lane) * 8],
                                       o_acc[i][dt], 0, 0, 0);
        }
    }

    // ---- epilogue ----
#pragma unroll
    for (int i = 0; i < 2; ++i) {
        const int mt = wave * 2 + i;
#pragma unroll
        for (int r = 0; r < 4; ++r) {
            const float inv_l = 1.0f / l_i[i][r];
            const int s = q0 + mt * 16 + fq * 4 + r;
#pragma unroll
            for (int dt = 0; dt < 8; ++dt)
                Ob[(size_t)s * QKDIM + h * HD + dt * 16 + fr] =
                    f2bf(o_acc[i][dt][r] * inv_l);
        }
    }
}

// ---------------------------------------------------------------------------
extern "C" void kernel_launch(void* const* d_in, const int* in_sizes, int n_in,
                              void* d_out, int out_size, void* d_ws, size_t ws_size,
                              hipStream_t stream) {
    const float* x  = (const float*)d_in[0];
    const float* Wq = (const float*)d_in[1];
    const float* Wk = (const float*)d_in[2];
    const float* Wv = (const float*)d_in[3];
    const float* Wo = (const float*)d_in[4];
    const float* qw = (const float*)d_in[5];
    const float* kw = (const float*)d_in[6];

    float* out     = (float*)d_out;
    float* cache_k = out + (size_t)S_LEN * DMODEL;
    float* cache_v = cache_k + (size_t)NKV * S_LEN * HD;

    float* ws = (float*)d_ws;
    float* qg = ws;
    float* kv = qg + (size_t)S_LEN * QKDIM;
    float* rg = kv + (size_t)S_LEN * KVCAT;

    // region R phase A: bf16 weights
    u16* Wqb = (u16*)rg;
    u16* Wkb = Wqb + (size_t)QKDIM * DMODEL;
    u16* Wvb = Wkb + (size_t)KVDIM * DMODEL;
    // region R phase B: bf16 Q, K, V^T + rope tables
    u16* qrb = (u16*)rg;
    u16* kcb = qrb + (size_t)NHEADS * S_LEN * HD;
    u16* vtb = kcb + (size_t)NKV * S_LEN * HD;
    float* ct = rg + (size_t)6400 * 1024;
    float* st = ct + S_LEN * 64;
    // qkv region phase C: attn out bf16 + Wo bf16
    u16* aob = (u16*)qg;
    u16* Wob = aob + (size_t)S_LEN * QKDIM;
    // x bf16 in d_out's out region
    u16* xb  = (u16*)out;

    // 1) converts
    f32_to_bf16_k<<<1024, 256, 0, stream>>>(x,  xb,  S_LEN * DMODEL / 4);
    f32_to_bf16_k<<<1024, 256, 0, stream>>>(Wq, Wqb, QKDIM * DMODEL / 4);
    f32_to_bf16_k<<<1024, 256, 0, stream>>>(Wk, Wkb, KVDIM * DMODEL / 4);
    f32_to_bf16_k<<<1024, 256, 0, stream>>>(Wv, Wvb, KVDIM * DMODEL / 4);

    // 2) fused QKV projection (BK=64)
    gemm_qkv<<<dim3((QKDIM + KVCAT)/128, S_LEN/128), 256, 0, stream>>>(
        (const __bf16*)xb, (const __bf16*)Wqb, (const __bf16*)Wkb, qg, kv);

    // 3) rope tables + RMSNorm/RoPE
    rope_table<<<S_LEN, 64, 0, stream>>>(ct, st);
    norm_rope<<<dim3(NHEADS + NKV, S_LEN), 128, 0, stream>>>(
        qg, kv, ct, st, qw, kw, qrb, cache_k, kcb, cache_v);

    // 4) V^T bf16
    v_transpose<<<dim3(NKV, S_LEN/64, HD/64), 256, 0, stream>>>(kv, vtb);

    // 5) Wo convert + MFMA flash attention (128-q tiles)
    f32_to_bf16_k<<<1024, 256, 0, stream>>>(Wo, Wob, DMODEL * QKDIM / 4);
    attn_mfma<<<dim3(S_LEN/128, NHEADS), 256, 0, stream>>>(
        (const __bf16*)qrb, (const __bf16*)kcb, (const __bf16*)vtb, aob);

    // 6) output projection (BK=64)
    gemm_bf16_nt<<<dim3(DMODEL/128, S_LEN/128), 256, 0, stream>>>(
        (const __bf16*)aob, (const __bf16*)Wob, out, S_LEN, DMODEL, QKDIM);
}

// Round 6
// 588.552 us; speedup vs baseline: 1.3173x; 1.3173x over previous
//
#include <hip/hip_runtime.h>
#include <hip/hip_bf16.h>
#include <math.h>

#define S_LEN  2048
#define DMODEL 2560
#define NHEADS 32
#define NKV    8
#define HD     128
#define QKDIM  (NHEADS * HD)   // 4096
#define KVDIM  (NKV * HD)      // 1024
#define KVCAT  (2 * KVDIM)     // 2048 (K and V concatenated per row)

typedef __bf16 bf16x8 __attribute__((ext_vector_type(8)));
typedef float  f32x4  __attribute__((ext_vector_type(4)));
typedef unsigned short u16;

#define AS1 __attribute__((address_space(1)))
#define AS3 __attribute__((address_space(3)))

__device__ __forceinline__ void load16_to_lds(const void* g, void* l) {
    __builtin_amdgcn_global_load_lds((const AS1 void*)g, (AS3 void*)l, 16, 0, 0);
}

__device__ __forceinline__ u16 f2bf(float f) {
    unsigned u = __builtin_bit_cast(unsigned, f);
    return (u16)((u + 0x7fff + ((u >> 16) & 1)) >> 16);   // RTNE
}

// ---------------------------------------------------------------------------
// Fused input convert: x | Wq | Wk | Wv -> bf16 in one launch.
// Weight outputs are contiguous (Wqb||Wkb||Wvb); x goes to its own dest.
// Segment boundaries in float4 units.
// ---------------------------------------------------------------------------
#define N4_X   (S_LEN * DMODEL / 4)          // 1310720
#define N4_WQ  (QKDIM * DMODEL / 4)          // 2621440
#define N4_WK  (KVDIM * DMODEL / 4)          // 655360
#define N4_ALL (N4_X + N4_WQ + 2 * N4_WK)    // 5242880

__global__ __launch_bounds__(256) void convert_inputs(const float* __restrict__ x,
                                                      const float* __restrict__ wq,
                                                      const float* __restrict__ wk,
                                                      const float* __restrict__ wv,
                                                      u16* __restrict__ xb,
                                                      u16* __restrict__ wb) {
    const int stride = gridDim.x * 256;
    for (int i = blockIdx.x * 256 + threadIdx.x; i < N4_ALL; i += stride) {
        const float4* src;
        ushort4* dst;
        if (i < N4_X) {
            src = (const float4*)x + i;
            dst = (ushort4*)xb + i;
        } else {
            const int j = i - N4_X;          // weight-region float4 index
            dst = (ushort4*)wb + j;
            if (j < N4_WQ)                  src = (const float4*)wq + j;
            else if (j < N4_WQ + N4_WK)     src = (const float4*)wk + (j - N4_WQ);
            else                            src = (const float4*)wv + (j - N4_WQ - N4_WK);
        }
        float4 v = *src;
        ushort4 r;
        r.x = f2bf(v.x); r.y = f2bf(v.y); r.z = f2bf(v.z); r.w = f2bf(v.w);
        *dst = r;
    }
}

// ---------------------------------------------------------------------------
// fp32 -> bf16 convert, 4 elements/thread, grid-stride. n4 = n/4.
// ---------------------------------------------------------------------------
__global__ __launch_bounds__(256) void f32_to_bf16_k(const float* __restrict__ in,
                                                     u16* __restrict__ out, int n4) {
    int i = blockIdx.x * 256 + threadIdx.x;
    const int stride = gridDim.x * 256;
    for (; i < n4; i += stride) {
        float4 v = ((const float4*)in)[i];
        ushort4 r;
        r.x = f2bf(v.x); r.y = f2bf(v.y); r.z = f2bf(v.z); r.w = f2bf(v.w);
        ((ushort4*)out)[i] = r;
    }
}

// ---------------------------------------------------------------------------
// RoPE table: ct/st[s][i] fp32, computed in double (131K threads, trivial).
// ---------------------------------------------------------------------------
__global__ __launch_bounds__(64) void rope_table(float* __restrict__ ct,
                                                 float* __restrict__ st) {
    const int s = blockIdx.x;
    const int i = threadIdx.x;           // 0..63
    const double invf = pow(5.0e6, -(double)i / 64.0);
    const double ang  = (double)s * invf;
    ct[s * 64 + i] = (float)cos(ang);
    st[s * 64 + i] = (float)sin(ang);
}

// ---------------------------------------------------------------------------
// bf16 MFMA NT GEMM, BK=64 (measured mild win vs BK=32 at this scale).
// LDS layout: [mtile(8)][khalf(2)][lane(64)][8] fragment-chunk order.
// ---------------------------------------------------------------------------
__global__ __launch_bounds__(256) void gemm_bf16_nt(const __bf16* __restrict__ A,
                                                    const __bf16* __restrict__ B,
                                                    float* __restrict__ C,
                                                    int M, int N, int K) {
    __shared__ __align__(16) __bf16 Als[128 * 64];   // 16 KB
    __shared__ __align__(16) __bf16 Bls[128 * 64];   // 16 KB
    const int tid  = threadIdx.x;
    const int lane = tid & 63;
    const int wave = tid >> 6;
    const int wm   = wave >> 1, wn = wave & 1;
    const int m0   = blockIdx.y * 128;
    const int n0   = blockIdx.x * 128;
    const int frow = lane & 15;
    const int fkq  = lane >> 4;

    f32x4 acc[4][4];
#pragma unroll
    for (int t = 0; t < 4; ++t)
#pragma unroll
        for (int u = 0; u < 4; ++u)
            acc[t][u] = (f32x4){0.f, 0.f, 0.f, 0.f};

    for (int k0 = 0; k0 < K; k0 += 64) {
        __syncthreads();
#pragma unroll
        for (int i = 0; i < 2; ++i) {
            const int mt  = i * 4 + wave;
            const int row = mt * 16 + frow;
#pragma unroll
            for (int kh = 0; kh < 2; ++kh) {
                const int col = k0 + kh * 32 + fkq * 8;
                load16_to_lds(A + (size_t)(m0 + row) * K + col,
                              &Als[(size_t)((mt * 2 + kh) * 64) * 8]);
                load16_to_lds(B + (size_t)(n0 + row) * K + col,
                              &Bls[(size_t)((mt * 2 + kh) * 64) * 8]);
            }
        }
        __syncthreads();

#pragma unroll
        for (int kh = 0; kh < 2; ++kh) {
            bf16x8 af[4], bfr[4];
#pragma unroll
            for (int t = 0; t < 4; ++t)
                af[t]  = *(const bf16x8*)&Als[(((wm * 4 + t) * 2 + kh) * 64 + lane) * 8];
#pragma unroll
            for (int u = 0; u < 4; ++u)
                bfr[u] = *(const bf16x8*)&Bls[(((wn * 4 + u) * 2 + kh) * 64 + lane) * 8];
#pragma unroll
            for (int t = 0; t < 4; ++t)
#pragma unroll
                for (int u = 0; u < 4; ++u)
                    acc[t][u] = __builtin_amdgcn_mfma_f32_16x16x32_bf16(
                                    af[t], bfr[u], acc[t][u], 0, 0, 0);
        }
    }

    const int crow = (lane >> 4) * 4;
    const int ccol = lane & 15;
#pragma unroll
    for (int t = 0; t < 4; ++t) {
        const int gr = m0 + (wm * 4 + t) * 16 + crow;
#pragma unroll
        for (int u = 0; u < 4; ++u) {
            const int gc = n0 + (wn * 4 + u) * 16 + ccol;
#pragma unroll
            for (int r = 0; r < 4; ++r)
                C[(size_t)(gr + r) * N + gc] = acc[t][u][r];
        }
    }
}

// ---------------------------------------------------------------------------
// Fused QKV GEMM, BK=64.  grid (48,16): n-tiles [0,32) -> Wq/Cq[2048][4096];
// [32,48) -> (Wk||Wv)/Ckv[2048][2048].  K = DMODEL = 2560 -> 40 iters.
// ---------------------------------------------------------------------------
__global__ __launch_bounds__(256) void gemm_qkv(const __bf16* __restrict__ A,
                                                const __bf16* __restrict__ Bq,
                                                const __bf16* __restrict__ Bkv,
                                                float* __restrict__ Cq,
                                                float* __restrict__ Ckv) {
    __shared__ __align__(16) __bf16 Als[128 * 64];
    __shared__ __align__(16) __bf16 Bls[128 * 64];
    const int K = DMODEL;
    const int n0g = blockIdx.x * 128;
    const __bf16* B;
    float* C;
    int ldc, n0;
    if (n0g < QKDIM) { B = Bq;  C = Cq;  ldc = QKDIM; n0 = n0g; }
    else             { B = Bkv; C = Ckv; ldc = KVCAT; n0 = n0g - QKDIM; }

    const int tid  = threadIdx.x;
    const int lane = tid & 63;
    const int wave = tid >> 6;
    const int wm   = wave >> 1, wn = wave & 1;
    const int m0   = blockIdx.y * 128;
    const int frow = lane & 15;
    const int fkq  = lane >> 4;

    f32x4 acc[4][4];
#pragma unroll
    for (int t = 0; t < 4; ++t)
#pragma unroll
        for (int u = 0; u < 4; ++u)
            acc[t][u] = (f32x4){0.f, 0.f, 0.f, 0.f};

    for (int k0 = 0; k0 < K; k0 += 64) {
        __syncthreads();
#pragma unroll
        for (int i = 0; i < 2; ++i) {
            const int mt  = i * 4 + wave;
            const int row = mt * 16 + frow;
#pragma unroll
            for (int kh = 0; kh < 2; ++kh) {
                const int col = k0 + kh * 32 + fkq * 8;
                load16_to_lds(A + (size_t)(m0 + row) * K + col,
                              &Als[(size_t)((mt * 2 + kh) * 64) * 8]);
                load16_to_lds(B + (size_t)(n0 + row) * K + col,
                              &Bls[(size_t)((mt * 2 + kh) * 64) * 8]);
            }
        }
        __syncthreads();

#pragma unroll
        for (int kh = 0; kh < 2; ++kh) {
            bf16x8 af[4], bfr[4];
#pragma unroll
            for (int t = 0; t < 4; ++t)
                af[t]  = *(const bf16x8*)&Als[(((wm * 4 + t) * 2 + kh) * 64 + lane) * 8];
#pragma unroll
            for (int u = 0; u < 4; ++u)
                bfr[u] = *(const bf16x8*)&Bls[(((wn * 4 + u) * 2 + kh) * 64 + lane) * 8];
#pragma unroll
            for (int t = 0; t < 4; ++t)
#pragma unroll
                for (int u = 0; u < 4; ++u)
                    acc[t][u] = __builtin_amdgcn_mfma_f32_16x16x32_bf16(
                                    af[t], bfr[u], acc[t][u], 0, 0, 0);
        }
    }

    const int crow = (lane >> 4) * 4;
    const int ccol = lane & 15;
#pragma unroll
    for (int t = 0; t < 4; ++t) {
        const int gr = m0 + (wm * 4 + t) * 16 + crow;
#pragma unroll
        for (int u = 0; u < 4; ++u) {
            const int gc = n0 + (wn * 4 + u) * 16 + ccol;
#pragma unroll
            for (int r = 0; r < 4; ++r)
                C[(size_t)(gr + r) * ldc + gc] = acc[t][u][r];
        }
    }
}

// ---------------------------------------------------------------------------
// Per-(s, head) RMSNorm + RoPE, table-driven.
// ---------------------------------------------------------------------------
__global__ __launch_bounds__(128) void norm_rope(const float* __restrict__ qg,
                                                 const float* __restrict__ kv,
                                                 const float* __restrict__ ct,
                                                 const float* __restrict__ st,
                                                 const float* __restrict__ qw,
                                                 const float* __restrict__ kw,
                                                 u16* __restrict__ qrb,
                                                 float* __restrict__ kc,
                                                 u16* __restrict__ kcb,
                                                 float* __restrict__ vc) {
    const int slot = blockIdx.x;   // 0..39
    const int s    = blockIdx.y;   // 0..2047
    const int d    = threadIdx.x;  // 0..127

    float x;
    const float* w;
    if (slot < NHEADS) {
        x = qg[(size_t)s * QKDIM + slot * HD + d];
        w = qw;
    } else {
        const int g = slot - NHEADS;
        x = kv[(size_t)s * KVCAT + g * HD + d];
        w = kw;
        vc[((size_t)g * S_LEN + s) * HD + d] =
            kv[(size_t)s * KVCAT + KVDIM + g * HD + d];
    }

    float ssum = x * x;
#pragma unroll
    for (int off = 1; off < 64; off <<= 1) ssum += __shfl_xor(ssum, off);
    __shared__ float red[2];
    __shared__ float ynorm[128];
    if ((d & 63) == 0) red[d >> 6] = ssum;
    __syncthreads();
    const float mean = (red[0] + red[1]) * (1.0f / 128.0f);
    const float y = x * rsqrtf(mean + 1e-6f) * w[d];
    ynorm[d] = y;
    __syncthreads();
    const float partner = ynorm[d ^ 64];

    const int i = d & 63;
    const float cs = ct[s * 64 + i];
    const float sn = st[s * 64 + i];
    const float outv = (d < 64) ? (y * cs - partner * sn)
                                : (y * cs + partner * sn);

    if (slot < NHEADS) {
        qrb[((size_t)slot * S_LEN + s) * HD + d] = f2bf(outv * 0.12751743f);
    } else {
        const int g = slot - NHEADS;
        kc [((size_t)g * S_LEN + s) * HD + d] = outv;
        kcb[((size_t)g * S_LEN + s) * HD + d] = f2bf(outv);
    }
}

// ---------------------------------------------------------------------------
// V transpose: kv fp32 [s][1024 + g*128+d]  ->  vtb bf16 [g][d][s]
// ---------------------------------------------------------------------------
__global__ __launch_bounds__(256) void v_transpose(const float* __restrict__ kv,
                                                   u16* __restrict__ vtb) {
    __shared__ float Ts[64][65];
    const int g  = blockIdx.x;
    const int s0 = blockIdx.y * 64;
    const int d0 = blockIdx.z * 64;
    const int tid = threadIdx.x;

    for (int e = tid; e < 64 * 16; e += 256) {
        const int r = e >> 4, c = (e & 15) << 2;
        float4 v = *(const float4*)(kv + (size_t)(s0 + r) * KVCAT + KVDIM
                                       + g * HD + d0 + c);
        Ts[r][c] = v.x; Ts[r][c+1] = v.y; Ts[r][c+2] = v.z; Ts[r][c+3] = v.w;
    }
    __syncthreads();
    for (int e = tid; e < 64 * 16; e += 256) {
        const int d = e >> 4, c = (e & 15) << 2;
        ushort4 o;
        o.x = f2bf(Ts[c+0][d]); o.y = f2bf(Ts[c+1][d]);
        o.z = f2bf(Ts[c+2][d]); o.w = f2bf(Ts[c+3][d]);
        *(ushort4*)(vtb + ((size_t)g * HD + d0 + d) * S_LEN + s0 + c) = o;
    }
}

// ---------------------------------------------------------------------------
// MFMA flash attention (round-4 64-query version, GRID SWAPPED for CU
// balance: x = head, y = q-tile).  Co-resident blocks on a CU then span
// q-tiles {q0, q0+8, q0+16, q0+24} instead of 4 identical lengths.
// LDS = 16 (K) + 16 (Q/V) + 8 (P) = 40KB -> 4 blocks/CU.
// ---------------------------------------------------------------------------
__global__ __launch_bounds__(256, 4) void attn_mfma(const __bf16* __restrict__ Qb,
                                                    const __bf16* __restrict__ Kb,
                                                    const __bf16* __restrict__ Vt,
                                                    u16* __restrict__ Ob) {
    __shared__ __align__(16) __bf16 Kls [4 * 4 * 64 * 8];  // 16KB
    __shared__ __align__(16) __bf16 QVls[8 * 2 * 64 * 8];  // 16KB (Q, then V)
    __shared__ __align__(16) __bf16 Pls [4 * 2 * 64 * 8];  // 8KB

    const int h    = blockIdx.x;        // swapped
    const int g    = h >> 2;
    const int q0   = blockIdx.y * 64;   // swapped
    const int tid  = threadIdx.x;
    const int lane = tid & 63;
    const int wave = tid >> 6;
    const int fr   = lane & 15;
    const int fq   = lane >> 4;

    // stage Q tile (wave w -> mtile w) into QVls, then hoist into registers
    {
        const __bf16* Qg = Qb + ((size_t)h * S_LEN + q0 + wave * 16 + fr) * HD;
#pragma unroll
        for (int ks = 0; ks < 4; ++ks)
            load16_to_lds(Qg + ks * 32 + fq * 8, &QVls[(size_t)((wave * 4 + ks) * 64) * 8]);
    }
    __syncthreads();   // drains vmcnt: Q visible in LDS
    bf16x8 aq[4];
#pragma unroll
    for (int ks = 0; ks < 4; ++ks)
        aq[ks] = *(const bf16x8*)&QVls[((wave * 4 + ks) * 64 + lane) * 8];

    float m_i[4], l_i[4];
    f32x4 o_acc[8];
#pragma unroll
    for (int r = 0; r < 4; ++r) { m_i[r] = -INFINITY; l_i[r] = 0.0f; }
#pragma unroll
    for (int dt = 0; dt < 8; ++dt) o_acc[dt] = (f32x4){0.f, 0.f, 0.f, 0.f};

    const int kt_max = blockIdx.y;      // swapped
    for (int kt = 0; kt <= kt_max; ++kt) {
        __syncthreads();   // prev iter's LDS reads (and Q hoist) done
        // stage K tile: wave w -> ntile w
        {
            const __bf16* Kg = Kb + ((size_t)g * S_LEN + kt * 64 + wave * 16 + fr) * HD;
#pragma unroll
            for (int ks = 0; ks < 4; ++ks)
                load16_to_lds(Kg + ks * 32 + fq * 8, &Kls[(size_t)((wave * 4 + ks) * 64) * 8]);
        }
        // stage V^T tile into QVls: wave w -> dtiles {2w, 2w+1}
#pragma unroll
        for (int i = 0; i < 2; ++i) {
            const int dt = wave * 2 + i;
            const __bf16* Vg = Vt + ((size_t)g * HD + dt * 16 + fr) * S_LEN + kt * 64;
#pragma unroll
            for (int ks = 0; ks < 2; ++ks)
                load16_to_lds(Vg + ks * 32 + fq * 8, &QVls[(size_t)((dt * 2 + ks) * 64) * 8]);
        }
        __syncthreads();   // staging complete

        // ---- QK^T ----
        f32x4 s_acc[4];
#pragma unroll
        for (int u = 0; u < 4; ++u) s_acc[u] = (f32x4){0.f, 0.f, 0.f, 0.f};
#pragma unroll
        for (int u = 0; u < 4; ++u)
#pragma unroll
            for (int ks = 0; ks < 4; ++ks)
                s_acc[u] = __builtin_amdgcn_mfma_f32_16x16x32_bf16(
                               aq[ks],
                               *(const bf16x8*)&Kls[((u * 4 + ks) * 64 + lane) * 8],
                               s_acc[u], 0, 0, 0);

        // ---- causal mask (diagonal tile only) ----
        if (kt == kt_max) {
#pragma unroll
            for (int u = 0; u < 4; ++u)
#pragma unroll
                for (int r = 0; r < 4; ++r)
                    if (kt * 64 + u * 16 + fr > q0 + wave * 16 + fq * 4 + r)
                        s_acc[u][r] = -INFINITY;
        }

        // ---- online softmax (row = fq*4+r; reduce over quad's 16 lanes) ----
#pragma unroll
        for (int r = 0; r < 4; ++r) {
            float mx = fmaxf(fmaxf(s_acc[0][r], s_acc[1][r]),
                             fmaxf(s_acc[2][r], s_acc[3][r]));
#pragma unroll
            for (int off = 1; off < 16; off <<= 1)
                mx = fmaxf(mx, __shfl_xor(mx, off));
            const float m_new = fmaxf(m_i[r], mx);
            const float alpha = exp2f(m_i[r] - m_new);
            m_i[r] = m_new;

            float p[4], psum = 0.0f;
#pragma unroll
            for (int u = 0; u < 4; ++u) {
                p[u] = exp2f(s_acc[u][r] - m_new);
                psum += p[u];
            }
#pragma unroll
            for (int off = 1; off < 16; off <<= 1)
                psum += __shfl_xor(psum, off);
            l_i[r] = l_i[r] * alpha + psum;

#pragma unroll
            for (int dt = 0; dt < 8; ++dt) o_acc[dt][r] *= alpha;

#pragma unroll
            for (int u = 0; u < 4; ++u) {
                const int k = u * 16 + fr;
                const int m = fq * 4 + r;
                const int idx = ((wave * 2 + (k >> 5)) * 64 + ((k >> 3) & 3) * 16 + m) * 8
                                + (k & 7);
                ((u16*)Pls)[idx] = f2bf(p[u]);
            }
        }

        // ---- PV (same-wave LDS write->read ordered) ----
        bf16x8 ap[2];
#pragma unroll
        for (int ks = 0; ks < 2; ++ks)
            ap[ks] = *(const bf16x8*)&Pls[((wave * 2 + ks) * 64 + lane) * 8];
#pragma unroll
        for (int dt = 0; dt < 8; ++dt)
#pragma unroll
            for (int ks = 0; ks < 2; ++ks)
                o_acc[dt] = __builtin_amdgcn_mfma_f32_16x16x32_bf16(
                                ap[ks],
                                *(const bf16x8*)&QVls[((dt * 2 + ks) * 64 + lane) * 8],
                                o_acc[dt], 0, 0, 0);
    }

    // ---- epilogue ----
#pragma unroll
    for (int r = 0; r < 4; ++r) {
        const float inv_l = 1.0f / l_i[r];
        const int s = q0 + wave * 16 + fq * 4 + r;
#pragma unroll
        for (int dt = 0; dt < 8; ++dt)
            Ob[(size_t)s * QKDIM + h * HD + dt * 16 + fr] = f2bf(o_acc[dt][r] * inv_l);
    }
}

// ---------------------------------------------------------------------------
extern "C" void kernel_launch(void* const* d_in, const int* in_sizes, int n_in,
                              void* d_out, int out_size, void* d_ws, size_t ws_size,
                              hipStream_t stream) {
    const float* x  = (const float*)d_in[0];
    const float* Wq = (const float*)d_in[1];
    const float* Wk = (const float*)d_in[2];
    const float* Wv = (const float*)d_in[3];
    const float* Wo = (const float*)d_in[4];
    const float* qw = (const float*)d_in[5];
    const float* kw = (const float*)d_in[6];

    float* out     = (float*)d_out;
    float* cache_k = out + (size_t)S_LEN * DMODEL;
    float* cache_v = cache_k + (size_t)NKV * S_LEN * HD;

    float* ws = (float*)d_ws;
    float* qg = ws;
    float* kv = qg + (size_t)S_LEN * QKDIM;
    float* rg = kv + (size_t)S_LEN * KVCAT;

    // region R phase A: bf16 weights (contiguous for fused convert)
    u16* Wqb = (u16*)rg;
    u16* Wkb = Wqb + (size_t)QKDIM * DMODEL;
    u16* Wvb = Wkb + (size_t)KVDIM * DMODEL;
    // region R phase B: bf16 Q, K, V^T + rope tables
    u16* qrb = (u16*)rg;
    u16* kcb = qrb + (size_t)NHEADS * S_LEN * HD;
    u16* vtb = kcb + (size_t)NKV * S_LEN * HD;
    float* ct = rg + (size_t)6400 * 1024;
    float* st = ct + S_LEN * 64;
    // qg+kv region phase C (dead after v_transpose): attn out bf16 + Wo bf16
    u16* aob = (u16*)qg;
    u16* Wob = aob + (size_t)S_LEN * QKDIM;
    // x bf16 in d_out's out region
    u16* xb  = (u16*)out;

    // 1) fused input converts (x | Wq | Wk | Wv)
    convert_inputs<<<4096, 256, 0, stream>>>(x, Wq, Wk, Wv, xb, Wqb);

    // 2) fused QKV projection (BK=64)
    gemm_qkv<<<dim3((QKDIM + KVCAT)/128, S_LEN/128), 256, 0, stream>>>(
        (const __bf16*)xb, (const __bf16*)Wqb, (const __bf16*)Wkb, qg, kv);

    // 3) rope tables + RMSNorm/RoPE
    rope_table<<<S_LEN, 64, 0, stream>>>(ct, st);
    norm_rope<<<dim3(NHEADS + NKV, S_LEN), 128, 0, stream>>>(
        qg, kv, ct, st, qw, kw, qrb, cache_k, kcb, cache_v);

    // 4) V^T bf16
    v_transpose<<<dim3(NKV, S_LEN/64, HD/64), 256, 0, stream>>>(kv, vtb);

    // 5) Wo convert + MFMA flash attention (64-q tiles, balanced grid)
    f32_to_bf16_k<<<1024, 256, 0, stream>>>(Wo, Wob, DMODEL * QKDIM / 4);
    attn_mfma<<<dim3(NHEADS, S_LEN/64), 256, 0, stream>>>(
        (const __bf16*)qrb, (const __bf16*)kcb, (const __bf16*)vtb, aob);

    // 6) output projection (BK=64)
    gemm_bf16_nt<<<dim3(DMODEL/128, S_LEN/128), 256, 0, stream>>>(
        (const __bf16*)aob, (const __bf16*)Wob, out, S_LEN, DMODEL, QKDIM);
}